// Round 15
// baseline (173.326 us; speedup 1.0000x reference)
//
#include <hip/hip_runtime.h>
#include <math.h>
#include <stdint.h>

#define H 2048
#define HH (H * H)
#define NB 256
#define NBK 1024                // regions (=buckets) per side
#define RPIX (HH / NBK)         // 4096 pixels per region
#define RLOG 12                 // log2(RPIX)
#define CH 16                   // u16 slots/segment: [0]=count, [1..15]=entries
#define CE 15                   // entry capacity per (bucket,chunk) segment
#define CQUADS 1024             // quads per chunk (4096 samples/side)
#define MAXCH 512               // max chunks (nidx <= 2,097,152)

// ws layout (fast path):
//   [0]       double accum               (8 B)
//   [64]      uint32 hist[2][768]        (6 KiB)  final histograms (spill+reduce)
//   [16384]   float  table[3][256]       (3 KiB)
//   [65536]   uint32 bits[HH/32]         (512 KiB) membership bitmask
//   [1 MiB]   uint32 histpart[4096][768] (12.6 MiB) per-block partial hists
//   [14 MiB]  u16    dlist[1024][MAXCH][16] (16 MiB)
//   [30 MiB]  u16    rlist[1024][MAXCH][16] (16 MiB)
#define OFF_HIST  64
#define OFF_TABLE 16384
#define OFF_BITS  65536
#define OFF_HPART ((size_t)1 << 20)
#define OFF_DLIST ((size_t)14 << 20)
#define OFF_RLIST ((size_t)30 << 20)
#define WS_FAST   ((size_t)46 << 20)

__global__ void k_init(uint32_t* __restrict__ ws32) {
    int tid = blockIdx.x * blockDim.x + threadIdx.x;
    int stride = gridDim.x * blockDim.x;
    uint4 z = {0u, 0u, 0u, 0u};
    // zero [0, 16384): accum + hist + table  (1024 uint4)
    uint4* a = (uint4*)ws32;
    for (int i = tid; i < 1024; i += stride) a[i] = z;
    // zero bits: 32768 uint4
    uint4* b = (uint4*)((char*)ws32 + OFF_BITS);
    for (int i = tid; i < 32768; i += stride) b[i] = z;
}

__device__ __forceinline__ float de_norm255(float x) {
    return fminf(fmaxf((x + 1.0f) * 0.5f, 0.0f), 1.0f) * 255.0f;
}

__device__ __forceinline__ uint32_t bin_of(float v, float m) {
    return (uint32_t)(de_norm255(v) * m);  // in [0,255], trunc==floor
}

#define E4(v, e) ((e) == 0 ? (v).x : (e) == 1 ? (v).y : (e) == 2 ? (v).z : (v).w)

// blockIdx.y: side = y>>1, half = y&1 (each block owns 512 buckets).
// Single-pass partition into fixed per-(bucket,chunk) 32 B segments (count
// embedded), flushed coalesced. 18 KiB LDS; grid ~4*nchunk.
__global__ __launch_bounds__(256) void k_bucket(
    const int* __restrict__ i0, const int* __restrict__ i1,
    const int* __restrict__ i2, const int* __restrict__ i3,
    unsigned short* __restrict__ dlist, unsigned short* __restrict__ rlist,
    const float* __restrict__ ref, const float* __restrict__ msrc,
    const float* __restrict__ tgt, const float* __restrict__ mtar,
    uint32_t* __restrict__ hist, uint32_t* __restrict__ bits,
    int nquad, int nchunk) {
    __shared__ __align__(16) unsigned short stag[512 * CH];  // 16 KiB
    __shared__ uint32_t lcnt[512];                           // 2 KiB
    int side = blockIdx.y >> 1;
    int half = blockIdx.y & 1;
    int chunk = blockIdx.x;
    for (int i = threadIdx.x; i < 512; i += 256) lcnt[i] = 0u;
    __syncthreads();
    const int* ia = side ? i2 : i0;
    const int* ib = side ? i3 : i1;
#pragma unroll
    for (int it = 0; it < CQUADS / 256; ++it) {
        int q = chunk * CQUADS + it * 256 + threadIdx.x;
        if (q < nquad) {
            int4 a = ((const int4*)ia)[q];
            int4 b = ((const int4*)ib)[q];
            int p[4] = {a.x * H + b.x, a.y * H + b.y, a.z * H + b.z, a.w * H + b.w};
#pragma unroll
            for (int j = 0; j < 4; ++j) {
                int bk = p[j] >> RLOG;
                if ((bk >> 9) != half) continue;
                int lb = bk & 511;
                uint32_t s = atomicAdd(&lcnt[lb], 1u);
                if (s < CE) {
                    stag[lb * CH + 1 + s] = (unsigned short)(p[j] & (RPIX - 1));
                } else {  // spill: ~1e-6/cell; correct, output-invariant slow path
                    int p0 = p[j];
                    if (side == 0) {
                        float m = msrc[p0];
                        atomicOr(&bits[p0 >> 5], 1u << (p0 & 31));
#pragma unroll
                        for (int c = 0; c < 3; ++c)
                            atomicAdd(&hist[c * NB + bin_of(ref[c * HH + p0], m)], 1u);
                    } else {
                        float m = mtar[p0];
#pragma unroll
                        for (int c = 0; c < 3; ++c)
                            atomicAdd(&hist[768 + c * NB + bin_of(tgt[c * HH + p0], m)], 1u);
                    }
                }
            }
        }
    }
    __syncthreads();
    for (int lb = threadIdx.x; lb < 512; lb += 256)
        stag[lb * CH] = (unsigned short)min(lcnt[lb], (uint32_t)CE);
    __syncthreads();
    // flush: 32 B per bucket segment (2 x uint4)
    unsigned short* glist = side ? rlist : dlist;
    for (int lb = threadIdx.x; lb < 512; lb += 256) {
        int bk = half * 512 + lb;
        const uint4* s4 = (const uint4*)&stag[lb * CH];
        uint4* g4 = (uint4*)(glist + ((size_t)bk * nchunk + chunk) * CH);
        g4[0] = s4[0];
        g4[1] = s4[1];
    }
}

#define PROCESS_QUAD(cw, m4, v0, v1, v2, qi)                                   \
    {                                                                          \
        uint32_t cnts[4] = {cw.x & 0xffffu, cw.x >> 16, cw.y & 0xffffu,        \
                            cw.y >> 16};                                       \
        _Pragma("unroll") for (int e = 0; e < 4; ++e) {                        \
            uint32_t cn = cnts[e];                                             \
            if (!cn) continue;                                                 \
            float mm = E4(m4, e);                                              \
            uint32_t c0 = bin_of(E4(v0, e), mm);                               \
            uint32_t c1 = bin_of(E4(v1, e), mm);                               \
            uint32_t c2 = bin_of(E4(v2, e), mm);                               \
            if (c0) atomicAdd(&s_h[c0], cn); else z0 += cn;                    \
            if (c1) atomicAdd(&s_h[NB + c1], cn); else z1 += cn;               \
            if (c2) atomicAdd(&s_h[2 * NB + c2], cn); else z2 += cn;           \
        }                                                                      \
        if (!side) {                                                           \
            uint32_t nib = (cnts[0] ? 1u : 0u) | (cnts[1] ? 2u : 0u) |         \
                           (cnts[2] ? 4u : 0u) | (cnts[3] ? 8u : 0u);          \
            atomicOr(&s_bits[(qi) >> 3], nib << (((qi) & 7) * 4));             \
        }                                                                      \
    }

// One block per (side, region, half): 4096 blocks, 7.3 KiB LDS.
// All 8 float4 loads issue unconditionally at kernel ENTRY; LDS zeroing and
// the Phase-A segment scan (independent uint4 pairs, half-filtered) run under
// that latency. After one barrier, compute is pure-register. Hist flush is
// plain coalesced stores to a private histpart slot (no global atomics).
__global__ __launch_bounds__(256) void k_bgather(
    const unsigned short* __restrict__ dlist, const unsigned short* __restrict__ rlist,
    const float* __restrict__ ref, const float* __restrict__ msrc,
    const float* __restrict__ tgt, const float* __restrict__ mtar,
    uint32_t* __restrict__ histpart, uint32_t* __restrict__ bits, int nchunk) {
    __shared__ uint32_t s_cnt[1024];     // 2048 px packed 2xu16 = 4 KiB
    __shared__ uint32_t s_h[3 * NB];     // 3 KiB
    __shared__ uint32_t s_bits[64];      // 256 B
    int bid = blockIdx.x;
    int side = bid >> 11;
    int b = (bid >> 1) & (NBK - 1);
    int half = bid & 1;
    const float* v = side ? tgt : ref;
    const float* m = side ? mtar : msrc;
    // entry loads: 2 quads/thread, unconditional
    int qi0 = threadIdx.x;
    int qi1 = threadIdx.x + 256;
    int g0 = b * (RPIX / 4) + half * 512 + qi0;
    int g1 = g0 + 256;
    float4 mA = ((const float4*)m)[g0];
    float4 a0 = ((const float4*)(v))[g0];
    float4 a1 = ((const float4*)(v + HH))[g0];
    float4 a2 = ((const float4*)(v + 2 * HH))[g0];
    float4 mB = ((const float4*)m)[g1];
    float4 b0 = ((const float4*)(v))[g1];
    float4 b1 = ((const float4*)(v + HH))[g1];
    float4 b2 = ((const float4*)(v + 2 * HH))[g1];
    // LDS zero overlaps load latency
    for (int i = threadIdx.x; i < 1024; i += 256) s_cnt[i] = 0u;
    for (int i = threadIdx.x; i < 3 * NB; i += 256) s_h[i] = 0u;
    if (threadIdx.x < 64) s_bits[threadIdx.x] = 0u;
    __syncthreads();
    // Phase A: wide segment reads, half-filtered scatter to LDS counts
    const unsigned short* lb = (side ? rlist : dlist) + (size_t)b * nchunk * CH;
    uint32_t htag = (uint32_t)half;
    for (int c = threadIdx.x; c < nchunk; c += 256) {
        const uint4* s4 = (const uint4*)(lb + (size_t)c * CH);
        uint4 A = s4[0];
        uint4 B = s4[1];                 // same 64B line: free
        int cnt = (int)(A.x & 0xffffu);
        uint32_t e[15];
        e[0] = A.x >> 16;
        e[1] = A.y & 0xffffu;  e[2] = A.y >> 16;
        e[3] = A.z & 0xffffu;  e[4] = A.z >> 16;
        e[5] = A.w & 0xffffu;  e[6] = A.w >> 16;
        e[7] = B.x & 0xffffu;  e[8] = B.x >> 16;
        e[9] = B.y & 0xffffu;  e[10] = B.y >> 16;
        e[11] = B.z & 0xffffu; e[12] = B.z >> 16;
        e[13] = B.w & 0xffffu; e[14] = B.w >> 16;
#pragma unroll
        for (int i = 0; i < 15; ++i)
            if (i < cnt && (e[i] >> 11) == htag) {
                uint32_t lp = e[i] & 2047u;
                atomicAdd(&s_cnt[lp >> 1], 1u << ((lp & 1) * 16));
            }
    }
    __syncthreads();
    // compute from registers + LDS counts
    uint32_t z0 = 0, z1 = 0, z2 = 0;
    uint2 cwA = ((const uint2*)s_cnt)[qi0];
    uint2 cwB = ((const uint2*)s_cnt)[qi1];
    if (cwA.x | cwA.y) PROCESS_QUAD(cwA, mA, a0, a1, a2, qi0);
    if (cwB.x | cwB.y) PROCESS_QUAD(cwB, mB, b0, b1, b2, qi1);
    if (z0) atomicAdd(&s_h[0], z0);
    if (z1) atomicAdd(&s_h[NB], z1);
    if (z2) atomicAdd(&s_h[2 * NB], z2);
    __syncthreads();
    // flush: plain coalesced stores, no global atomics
    uint32_t* hp = histpart + (size_t)bid * 768;
    for (int i = threadIdx.x; i < 3 * NB; i += 256) hp[i] = s_h[i];
    if (!side && threadIdx.x < 64) {
        uint32_t* gb = bits + b * (RPIX / 32) + half * 64;
        uint32_t sb = s_bits[threadIdx.x];
        gb[threadIdx.x] = gb[threadIdx.x] | sb;  // pre-pass spill bits preserved
    }
}

// 16 blocks x 256 threads: coalesced sum of histpart into hist.
__global__ void k_reduce(const uint32_t* __restrict__ histpart,
                         uint32_t* __restrict__ hist) {
    int side = blockIdx.x >> 3;
    int seg = blockIdx.x & 7;
    uint32_t a0 = 0, a1 = 0, a2 = 0;
    int base = side * 2048 + seg * 256;
    for (int k = 0; k < 256; ++k) {
        const uint32_t* hp = histpart + (size_t)(base + k) * 768;
        a0 += hp[threadIdx.x];
        a1 += hp[threadIdx.x + 256];
        a2 += hp[threadIdx.x + 512];
    }
    atomicAdd(&hist[side * 768 + threadIdx.x], a0);
    atomicAdd(&hist[side * 768 + threadIdx.x + 256], a1);
    atomicAdd(&hist[side * 768 + threadIdx.x + 512], a2);
}

// Monolithic fallback (any ws): gather floats via LLC + bits mask.
__global__ void k_hist_fb(const float* __restrict__ tgt, const float* __restrict__ ref,
                          const float* __restrict__ msrc, const float* __restrict__ mtar,
                          const int* __restrict__ i0, const int* __restrict__ i1,
                          const int* __restrict__ i2, const int* __restrict__ i3,
                          uint32_t* __restrict__ hist, uint32_t* __restrict__ bits,
                          int nidx) {
    __shared__ uint32_t lh[6 * NB];
    for (int i = threadIdx.x; i < 6 * NB; i += blockDim.x) lh[i] = 0u;
    __syncthreads();
    int stride = gridDim.x * blockDim.x;
    for (int k = blockIdx.x * blockDim.x + threadIdx.x; k < nidx; k += stride) {
        int pa = i0[k] * H + i1[k];
        int pb = i2[k] * H + i3[k];
        float ms = msrc[pa];
        float mt = mtar[pb];
        atomicOr(&bits[pa >> 5], 1u << (pa & 31));
#pragma unroll
        for (int c = 0; c < 3; ++c) {
            atomicAdd(&lh[c * NB + bin_of(ref[c * HH + pa], ms)], 1u);
            atomicAdd(&lh[(3 + c) * NB + bin_of(tgt[c * HH + pb], mt)], 1u);
        }
    }
    __syncthreads();
    for (int i = threadIdx.x; i < 6 * NB; i += blockDim.x)
        if (lh[i]) atomicAdd(&hist[i], lh[i]);   // lh layout == hist layout
}

// 3 blocks (one per channel) x 256 threads.
__global__ void k_table(const uint32_t* __restrict__ hist, float* __restrict__ table) {
    int c = blockIdx.x;
    int t = threadIdx.x;
    __shared__ uint32_t cdd[NB], crr[NB];
    __shared__ float r[NB], a[NB];
    cdd[t] = hist[c * NB + t];
    crr[t] = hist[768 + c * NB + t];
    __syncthreads();
    if (t == 0) {
        uint32_t s = 0;
        for (int i = 0; i < NB; ++i) { s += cdd[i]; cdd[i] = s; }
        s = 0;
        for (int i = 0; i < NB; ++i) { s += crr[i]; crr[i] = s; }
    }
    __syncthreads();
    float totd = (float)cdd[NB - 1];
    float totr = (float)crr[NB - 1];
    r[t] = (float)cdd[t] / totd;
    a[t] = (float)crr[t] / totr;
    __syncthreads();
    float out;
    if (t == 0) {
        out = 0.0f;
    } else if (t == NB - 1) {
        out = (float)(NB - 1);
    } else {
        float ri = r[t];
        int j = -1;
        for (int jj = 0; jj < NB - 1; ++jj) {
            if (ri >= a[jj] && ri <= a[jj + 1]) { j = jj; break; }
        }
        out = (j >= 0) ? (float)(j + 1) : (float)t;
    }
    table[c * NB + t] = out;
}

// float4-vectorized loss; membership from bits; table in LDS.
__global__ void k_loss(const float* __restrict__ inp, const float* __restrict__ ref,
                       const float* __restrict__ msrc, const uint32_t* __restrict__ bits,
                       const float* __restrict__ table, double* __restrict__ accum) {
    __shared__ float tl[3 * NB];
    for (int i = threadIdx.x; i < 3 * NB; i += blockDim.x) tl[i] = table[i];
    __syncthreads();
    float part = 0.0f;
    int stride = gridDim.x * blockDim.x;
    for (int q = blockIdx.x * blockDim.x + threadIdx.x; q < HH / 4; q += stride) {
        float4 m4 = ((const float4*)msrc)[q];
        uint32_t nib = bits[q >> 3] >> ((q & 7) * 4);
#pragma unroll
        for (int c = 0; c < 3; ++c) {
            float4 iv = ((const float4*)(inp + c * HH))[q];
            float4 rv = ((const float4*)(ref + c * HH))[q];
#pragma unroll
            for (int e = 0; e < 4; ++e) {
                float m = E4(m4, e);
                float im = de_norm255(E4(iv, e)) * m;
                float r = de_norm255(E4(rv, e)) * m;
                float match;
                if ((nib >> e) & 1u)
                    match = tl[c * NB + (int)fminf(fmaxf(r, 0.0f), 255.0f)];
                else
                    match = r;
                part += fabsf(im - match);
            }
        }
    }
#pragma unroll
    for (int off = 32; off > 0; off >>= 1) part += __shfl_down(part, off);
    __shared__ float wsum[4];
    int lane = threadIdx.x & 63;
    int wid = threadIdx.x >> 6;
    if (lane == 0) wsum[wid] = part;
    __syncthreads();
    if (threadIdx.x == 0)
        atomicAdd(accum, (double)(wsum[0] + wsum[1] + wsum[2] + wsum[3]));
}

__global__ void k_final(const double* __restrict__ accum, float* __restrict__ out) {
    if (threadIdx.x == 0 && blockIdx.x == 0)
        out[0] = (float)(*accum / (double)(3.0 * (double)HH));
}

extern "C" void kernel_launch(void* const* d_in, const int* in_sizes, int n_in,
                              void* d_out, int out_size, void* d_ws, size_t ws_size,
                              hipStream_t stream) {
    const float* input  = (const float*)d_in[0];
    const float* target = (const float*)d_in[1];
    const float* ref    = (const float*)d_in[2];
    const float* msrc   = (const float*)d_in[3];
    const float* mtar   = (const float*)d_in[4];
    const int* i0 = (const int*)d_in[5];
    const int* i1 = (const int*)d_in[6];
    const int* i2 = (const int*)d_in[7];
    const int* i3 = (const int*)d_in[8];
    int nidx = in_sizes[5];

    char* ws = (char*)d_ws;
    double*   accum = (double*)(ws);
    uint32_t* hist  = (uint32_t*)(ws + OFF_HIST);
    float*    table = (float*)(ws + OFF_TABLE);
    uint32_t* bits  = (uint32_t*)(ws + OFF_BITS);

    k_init<<<512, 256, 0, stream>>>((uint32_t*)ws);

    int nquad = nidx / 4;
    int nchunk = (nquad + CQUADS - 1) / CQUADS;
    if (ws_size >= WS_FAST && (nidx & 3) == 0 && nchunk <= MAXCH) {
        uint32_t* histpart = (uint32_t*)(ws + OFF_HPART);
        unsigned short* dlist = (unsigned short*)(ws + OFF_DLIST);
        unsigned short* rlist = (unsigned short*)(ws + OFF_RLIST);
        dim3 bgrid(nchunk, 4);
        k_bucket<<<bgrid, 256, 0, stream>>>(
            i0, i1, i2, i3, dlist, rlist, ref, msrc, target, mtar,
            hist, bits, nquad, nchunk);
        k_bgather<<<4096, 256, 0, stream>>>(dlist, rlist, ref, msrc, target, mtar,
                                            histpart, bits, nchunk);
        k_reduce<<<16, 256, 0, stream>>>(histpart, hist);
    } else {
        k_hist_fb<<<2048, 256, 0, stream>>>(target, ref, msrc, mtar, i0, i1, i2, i3,
                                            hist, bits, nidx);
    }
    k_table<<<3, 256, 0, stream>>>(hist, table);
    k_loss<<<2048, 256, 0, stream>>>(input, ref, msrc, bits, table, accum);
    k_final<<<1, 64, 0, stream>>>(accum, (float*)d_out);
}

// Round 16
// 155.752 us; speedup vs baseline: 1.1128x; 1.1128x over previous
//
#include <hip/hip_runtime.h>
#include <math.h>
#include <stdint.h>

#define H 2048
#define HH (H * H)
#define NB 256
#define NBK 1024                // regions (=buckets) per side
#define RPIX (HH / NBK)         // 4096 pixels per region
#define RLOG 12                 // log2(RPIX)
#define CH 16                   // u16 slots/segment: [0]=count, [1..15]=entries
#define CE 15                   // entry capacity per (bucket,chunk) segment
#define CQUADS 1024             // quads per chunk (4096 samples/side)
#define MAXCH 512               // max chunks (nidx <= 2,097,152)

// ws layout (fast path):
//   [0]       double accum               (8 B)
//   [64]      uint32 hist[2][768]        (6 KiB)  final histograms (spill+reduce)
//   [16384]   float  table[3][256]       (3 KiB)
//   [65536]   uint32 bits[HH/32]         (512 KiB) membership bitmask
//   [1 MiB]   uint32 histpart[4096][768] (12.6 MiB) per-block partial hists
//   [14 MiB]  u16    dlist[1024][MAXCH][16] (16 MiB)
//   [30 MiB]  u16    rlist[1024][MAXCH][16] (16 MiB)
#define OFF_HIST  64
#define OFF_TABLE 16384
#define OFF_BITS  65536
#define OFF_HPART ((size_t)1 << 20)
#define OFF_DLIST ((size_t)14 << 20)
#define OFF_RLIST ((size_t)30 << 20)
#define WS_FAST   ((size_t)46 << 20)

__global__ void k_init(uint32_t* __restrict__ ws32) {
    int tid = blockIdx.x * blockDim.x + threadIdx.x;
    int stride = gridDim.x * blockDim.x;
    uint4 z = {0u, 0u, 0u, 0u};
    // zero [0, 16384): accum + hist + table  (1024 uint4)
    uint4* a = (uint4*)ws32;
    for (int i = tid; i < 1024; i += stride) a[i] = z;
    // zero bits: 32768 uint4
    uint4* b = (uint4*)((char*)ws32 + OFF_BITS);
    for (int i = tid; i < 32768; i += stride) b[i] = z;
}

__device__ __forceinline__ float de_norm255(float x) {
    return fminf(fmaxf((x + 1.0f) * 0.5f, 0.0f), 1.0f) * 255.0f;
}

__device__ __forceinline__ uint32_t bin_of(float v, float m) {
    return (uint32_t)(de_norm255(v) * m);  // in [0,255], trunc==floor
}

#define E4(v, e) ((e) == 0 ? (v).x : (e) == 1 ? (v).y : (e) == 2 ? (v).z : (v).w)

// blockIdx.y: side = y>>1, half = y&1 (each block owns 512 buckets).
// Single-pass partition into fixed per-(bucket,chunk) 32 B segments (count
// embedded), flushed coalesced. 18 KiB LDS; grid ~4*nchunk.
__global__ __launch_bounds__(256) void k_bucket(
    const int* __restrict__ i0, const int* __restrict__ i1,
    const int* __restrict__ i2, const int* __restrict__ i3,
    unsigned short* __restrict__ dlist, unsigned short* __restrict__ rlist,
    const float* __restrict__ ref, const float* __restrict__ msrc,
    const float* __restrict__ tgt, const float* __restrict__ mtar,
    uint32_t* __restrict__ hist, uint32_t* __restrict__ bits,
    int nquad, int nchunk) {
    __shared__ __align__(16) unsigned short stag[512 * CH];  // 16 KiB
    __shared__ uint32_t lcnt[512];                           // 2 KiB
    int side = blockIdx.y >> 1;
    int half = blockIdx.y & 1;
    int chunk = blockIdx.x;
    for (int i = threadIdx.x; i < 512; i += 256) lcnt[i] = 0u;
    __syncthreads();
    const int* ia = side ? i2 : i0;
    const int* ib = side ? i3 : i1;
#pragma unroll
    for (int it = 0; it < CQUADS / 256; ++it) {
        int q = chunk * CQUADS + it * 256 + threadIdx.x;
        if (q < nquad) {
            int4 a = ((const int4*)ia)[q];
            int4 b = ((const int4*)ib)[q];
            int p[4] = {a.x * H + b.x, a.y * H + b.y, a.z * H + b.z, a.w * H + b.w};
#pragma unroll
            for (int j = 0; j < 4; ++j) {
                int bk = p[j] >> RLOG;
                if ((bk >> 9) != half) continue;
                int lb = bk & 511;
                uint32_t s = atomicAdd(&lcnt[lb], 1u);
                if (s < CE) {
                    stag[lb * CH + 1 + s] = (unsigned short)(p[j] & (RPIX - 1));
                } else {  // spill: ~1e-6/cell; correct, output-invariant slow path
                    int p0 = p[j];
                    if (side == 0) {
                        float m = msrc[p0];
                        atomicOr(&bits[p0 >> 5], 1u << (p0 & 31));
#pragma unroll
                        for (int c = 0; c < 3; ++c)
                            atomicAdd(&hist[c * NB + bin_of(ref[c * HH + p0], m)], 1u);
                    } else {
                        float m = mtar[p0];
#pragma unroll
                        for (int c = 0; c < 3; ++c)
                            atomicAdd(&hist[768 + c * NB + bin_of(tgt[c * HH + p0], m)], 1u);
                    }
                }
            }
        }
    }
    __syncthreads();
    for (int lb = threadIdx.x; lb < 512; lb += 256)
        stag[lb * CH] = (unsigned short)min(lcnt[lb], (uint32_t)CE);
    __syncthreads();
    // flush: 32 B per bucket segment (2 x uint4)
    unsigned short* glist = side ? rlist : dlist;
    for (int lb = threadIdx.x; lb < 512; lb += 256) {
        int bk = half * 512 + lb;
        const uint4* s4 = (const uint4*)&stag[lb * CH];
        uint4* g4 = (uint4*)(glist + ((size_t)bk * nchunk + chunk) * CH);
        g4[0] = s4[0];
        g4[1] = s4[1];
    }
}

#define PROCESS_QUAD(cw, m4, v0, v1, v2, qi)                                   \
    {                                                                          \
        uint32_t cnts[4] = {cw.x & 0xffffu, cw.x >> 16, cw.y & 0xffffu,        \
                            cw.y >> 16};                                       \
        _Pragma("unroll") for (int e = 0; e < 4; ++e) {                        \
            uint32_t cn = cnts[e];                                             \
            if (!cn) continue;                                                 \
            float mm = E4(m4, e);                                              \
            uint32_t c0 = bin_of(E4(v0, e), mm);                               \
            uint32_t c1 = bin_of(E4(v1, e), mm);                               \
            uint32_t c2 = bin_of(E4(v2, e), mm);                               \
            if (c0) atomicAdd(&s_h[c0], cn); else z0 += cn;                    \
            if (c1) atomicAdd(&s_h[NB + c1], cn); else z1 += cn;               \
            if (c2) atomicAdd(&s_h[2 * NB + c2], cn); else z2 += cn;           \
        }                                                                      \
        if (!side) {                                                           \
            uint32_t nib = (cnts[0] ? 1u : 0u) | (cnts[1] ? 2u : 0u) |         \
                           (cnts[2] ? 4u : 0u) | (cnts[3] ? 8u : 0u);          \
            atomicOr(&s_bits[(qi) >> 3], nib << (((qi) & 7) * 4));             \
        }                                                                      \
    }

// One block per (side, region, half): 4096 blocks, 7.3 KiB LDS.
// All 8 float4 loads issue unconditionally at kernel ENTRY; LDS zeroing and
// the Phase-A segment scan (independent uint4 pairs, half-filtered) run under
// that latency. After one barrier, compute is pure-register. Hist flush is
// plain coalesced stores to a private histpart slot (no global atomics).
__global__ __launch_bounds__(256) void k_bgather(
    const unsigned short* __restrict__ dlist, const unsigned short* __restrict__ rlist,
    const float* __restrict__ ref, const float* __restrict__ msrc,
    const float* __restrict__ tgt, const float* __restrict__ mtar,
    uint32_t* __restrict__ histpart, uint32_t* __restrict__ bits, int nchunk) {
    __shared__ uint32_t s_cnt[1024];     // 2048 px packed 2xu16 = 4 KiB
    __shared__ uint32_t s_h[3 * NB];     // 3 KiB
    __shared__ uint32_t s_bits[64];      // 256 B
    int bid = blockIdx.x;
    int side = bid >> 11;
    int b = (bid >> 1) & (NBK - 1);
    int half = bid & 1;
    const float* v = side ? tgt : ref;
    const float* m = side ? mtar : msrc;
    // entry loads: 2 quads/thread, unconditional
    int qi0 = threadIdx.x;
    int qi1 = threadIdx.x + 256;
    int g0 = b * (RPIX / 4) + half * 512 + qi0;
    int g1 = g0 + 256;
    float4 mA = ((const float4*)m)[g0];
    float4 a0 = ((const float4*)(v))[g0];
    float4 a1 = ((const float4*)(v + HH))[g0];
    float4 a2 = ((const float4*)(v + 2 * HH))[g0];
    float4 mB = ((const float4*)m)[g1];
    float4 b0 = ((const float4*)(v))[g1];
    float4 b1 = ((const float4*)(v + HH))[g1];
    float4 b2 = ((const float4*)(v + 2 * HH))[g1];
    // LDS zero overlaps load latency
    for (int i = threadIdx.x; i < 1024; i += 256) s_cnt[i] = 0u;
    for (int i = threadIdx.x; i < 3 * NB; i += 256) s_h[i] = 0u;
    if (threadIdx.x < 64) s_bits[threadIdx.x] = 0u;
    __syncthreads();
    // Phase A: wide segment reads, half-filtered scatter to LDS counts
    const unsigned short* lb = (side ? rlist : dlist) + (size_t)b * nchunk * CH;
    uint32_t htag = (uint32_t)half;
    for (int c = threadIdx.x; c < nchunk; c += 256) {
        const uint4* s4 = (const uint4*)(lb + (size_t)c * CH);
        uint4 A = s4[0];
        uint4 B = s4[1];                 // same 64B line: free
        int cnt = (int)(A.x & 0xffffu);
        uint32_t e[15];
        e[0] = A.x >> 16;
        e[1] = A.y & 0xffffu;  e[2] = A.y >> 16;
        e[3] = A.z & 0xffffu;  e[4] = A.z >> 16;
        e[5] = A.w & 0xffffu;  e[6] = A.w >> 16;
        e[7] = B.x & 0xffffu;  e[8] = B.x >> 16;
        e[9] = B.y & 0xffffu;  e[10] = B.y >> 16;
        e[11] = B.z & 0xffffu; e[12] = B.z >> 16;
        e[13] = B.w & 0xffffu; e[14] = B.w >> 16;
#pragma unroll
        for (int i = 0; i < 15; ++i)
            if (i < cnt && (e[i] >> 11) == htag) {
                uint32_t lp = e[i] & 2047u;
                atomicAdd(&s_cnt[lp >> 1], 1u << ((lp & 1) * 16));
            }
    }
    __syncthreads();
    // compute from registers + LDS counts
    uint32_t z0 = 0, z1 = 0, z2 = 0;
    uint2 cwA = ((const uint2*)s_cnt)[qi0];
    uint2 cwB = ((const uint2*)s_cnt)[qi1];
    if (cwA.x | cwA.y) PROCESS_QUAD(cwA, mA, a0, a1, a2, qi0);
    if (cwB.x | cwB.y) PROCESS_QUAD(cwB, mB, b0, b1, b2, qi1);
    if (z0) atomicAdd(&s_h[0], z0);
    if (z1) atomicAdd(&s_h[NB], z1);
    if (z2) atomicAdd(&s_h[2 * NB], z2);
    __syncthreads();
    // flush: plain coalesced stores, no global atomics
    uint32_t* hp = histpart + (size_t)bid * 768;
    for (int i = threadIdx.x; i < 3 * NB; i += 256) hp[i] = s_h[i];
    if (!side && threadIdx.x < 64) {
        uint32_t* gb = bits + b * (RPIX / 32) + half * 64;
        uint32_t sb = s_bits[threadIdx.x];
        gb[threadIdx.x] = gb[threadIdx.x] | sb;  // pre-pass spill bits preserved
    }
}

// 128 blocks x 256 threads: each block sums 32 parts (unrolled -> 24
// independent loads in flight), one atomic per bin per block.
__global__ void k_reduce(const uint32_t* __restrict__ histpart,
                         uint32_t* __restrict__ hist) {
    int base = blockIdx.x * 32;          // parts [0,2048)=side0, [2048,4096)=side1
    uint32_t a0 = 0, a1 = 0, a2 = 0;
#pragma unroll 8
    for (int k = 0; k < 32; ++k) {
        const uint32_t* hp = histpart + (size_t)(base + k) * 768;
        a0 += hp[threadIdx.x];
        a1 += hp[threadIdx.x + 256];
        a2 += hp[threadIdx.x + 512];
    }
    int side = base >> 11;
    atomicAdd(&hist[side * 768 + threadIdx.x], a0);
    atomicAdd(&hist[side * 768 + threadIdx.x + 256], a1);
    atomicAdd(&hist[side * 768 + threadIdx.x + 512], a2);
}

// Monolithic fallback (any ws): gather floats via LLC + bits mask.
__global__ void k_hist_fb(const float* __restrict__ tgt, const float* __restrict__ ref,
                          const float* __restrict__ msrc, const float* __restrict__ mtar,
                          const int* __restrict__ i0, const int* __restrict__ i1,
                          const int* __restrict__ i2, const int* __restrict__ i3,
                          uint32_t* __restrict__ hist, uint32_t* __restrict__ bits,
                          int nidx) {
    __shared__ uint32_t lh[6 * NB];
    for (int i = threadIdx.x; i < 6 * NB; i += blockDim.x) lh[i] = 0u;
    __syncthreads();
    int stride = gridDim.x * blockDim.x;
    for (int k = blockIdx.x * blockDim.x + threadIdx.x; k < nidx; k += stride) {
        int pa = i0[k] * H + i1[k];
        int pb = i2[k] * H + i3[k];
        float ms = msrc[pa];
        float mt = mtar[pb];
        atomicOr(&bits[pa >> 5], 1u << (pa & 31));
#pragma unroll
        for (int c = 0; c < 3; ++c) {
            atomicAdd(&lh[c * NB + bin_of(ref[c * HH + pa], ms)], 1u);
            atomicAdd(&lh[(3 + c) * NB + bin_of(tgt[c * HH + pb], mt)], 1u);
        }
    }
    __syncthreads();
    for (int i = threadIdx.x; i < 6 * NB; i += blockDim.x)
        if (lh[i]) atomicAdd(&hist[i], lh[i]);   // lh layout == hist layout
}

// 3 blocks (one per channel) x 256 threads.
__global__ void k_table(const uint32_t* __restrict__ hist, float* __restrict__ table) {
    int c = blockIdx.x;
    int t = threadIdx.x;
    __shared__ uint32_t cdd[NB], crr[NB];
    __shared__ float r[NB], a[NB];
    cdd[t] = hist[c * NB + t];
    crr[t] = hist[768 + c * NB + t];
    __syncthreads();
    if (t == 0) {
        uint32_t s = 0;
        for (int i = 0; i < NB; ++i) { s += cdd[i]; cdd[i] = s; }
        s = 0;
        for (int i = 0; i < NB; ++i) { s += crr[i]; crr[i] = s; }
    }
    __syncthreads();
    float totd = (float)cdd[NB - 1];
    float totr = (float)crr[NB - 1];
    r[t] = (float)cdd[t] / totd;
    a[t] = (float)crr[t] / totr;
    __syncthreads();
    float out;
    if (t == 0) {
        out = 0.0f;
    } else if (t == NB - 1) {
        out = (float)(NB - 1);
    } else {
        float ri = r[t];
        int j = -1;
        for (int jj = 0; jj < NB - 1; ++jj) {
            if (ri >= a[jj] && ri <= a[jj + 1]) { j = jj; break; }
        }
        out = (j >= 0) ? (float)(j + 1) : (float)t;
    }
    table[c * NB + t] = out;
}

// float4-vectorized loss; membership from bits; table in LDS.
__global__ void k_loss(const float* __restrict__ inp, const float* __restrict__ ref,
                       const float* __restrict__ msrc, const uint32_t* __restrict__ bits,
                       const float* __restrict__ table, double* __restrict__ accum) {
    __shared__ float tl[3 * NB];
    for (int i = threadIdx.x; i < 3 * NB; i += blockDim.x) tl[i] = table[i];
    __syncthreads();
    float part = 0.0f;
    int stride = gridDim.x * blockDim.x;
    for (int q = blockIdx.x * blockDim.x + threadIdx.x; q < HH / 4; q += stride) {
        float4 m4 = ((const float4*)msrc)[q];
        uint32_t nib = bits[q >> 3] >> ((q & 7) * 4);
#pragma unroll
        for (int c = 0; c < 3; ++c) {
            float4 iv = ((const float4*)(inp + c * HH))[q];
            float4 rv = ((const float4*)(ref + c * HH))[q];
#pragma unroll
            for (int e = 0; e < 4; ++e) {
                float m = E4(m4, e);
                float im = de_norm255(E4(iv, e)) * m;
                float r = de_norm255(E4(rv, e)) * m;
                float match;
                if ((nib >> e) & 1u)
                    match = tl[c * NB + (int)fminf(fmaxf(r, 0.0f), 255.0f)];
                else
                    match = r;
                part += fabsf(im - match);
            }
        }
    }
#pragma unroll
    for (int off = 32; off > 0; off >>= 1) part += __shfl_down(part, off);
    __shared__ float wsum[4];
    int lane = threadIdx.x & 63;
    int wid = threadIdx.x >> 6;
    if (lane == 0) wsum[wid] = part;
    __syncthreads();
    if (threadIdx.x == 0)
        atomicAdd(accum, (double)(wsum[0] + wsum[1] + wsum[2] + wsum[3]));
}

__global__ void k_final(const double* __restrict__ accum, float* __restrict__ out) {
    if (threadIdx.x == 0 && blockIdx.x == 0)
        out[0] = (float)(*accum / (double)(3.0 * (double)HH));
}

extern "C" void kernel_launch(void* const* d_in, const int* in_sizes, int n_in,
                              void* d_out, int out_size, void* d_ws, size_t ws_size,
                              hipStream_t stream) {
    const float* input  = (const float*)d_in[0];
    const float* target = (const float*)d_in[1];
    const float* ref    = (const float*)d_in[2];
    const float* msrc   = (const float*)d_in[3];
    const float* mtar   = (const float*)d_in[4];
    const int* i0 = (const int*)d_in[5];
    const int* i1 = (const int*)d_in[6];
    const int* i2 = (const int*)d_in[7];
    const int* i3 = (const int*)d_in[8];
    int nidx = in_sizes[5];

    char* ws = (char*)d_ws;
    double*   accum = (double*)(ws);
    uint32_t* hist  = (uint32_t*)(ws + OFF_HIST);
    float*    table = (float*)(ws + OFF_TABLE);
    uint32_t* bits  = (uint32_t*)(ws + OFF_BITS);

    k_init<<<512, 256, 0, stream>>>((uint32_t*)ws);

    int nquad = nidx / 4;
    int nchunk = (nquad + CQUADS - 1) / CQUADS;
    if (ws_size >= WS_FAST && (nidx & 3) == 0 && nchunk <= MAXCH) {
        uint32_t* histpart = (uint32_t*)(ws + OFF_HPART);
        unsigned short* dlist = (unsigned short*)(ws + OFF_DLIST);
        unsigned short* rlist = (unsigned short*)(ws + OFF_RLIST);
        dim3 bgrid(nchunk, 4);
        k_bucket<<<bgrid, 256, 0, stream>>>(
            i0, i1, i2, i3, dlist, rlist, ref, msrc, target, mtar,
            hist, bits, nquad, nchunk);
        k_bgather<<<4096, 256, 0, stream>>>(dlist, rlist, ref, msrc, target, mtar,
                                            histpart, bits, nchunk);
        k_reduce<<<128, 256, 0, stream>>>(histpart, hist);
    } else {
        k_hist_fb<<<2048, 256, 0, stream>>>(target, ref, msrc, mtar, i0, i1, i2, i3,
                                            hist, bits, nidx);
    }
    k_table<<<3, 256, 0, stream>>>(hist, table);
    k_loss<<<2048, 256, 0, stream>>>(input, ref, msrc, bits, table, accum);
    k_final<<<1, 64, 0, stream>>>(accum, (float*)d_out);
}